// Round 1
// baseline (155.406 us; speedup 1.0000x reference)
//
#include <hip/hip_runtime.h>
#include <hip/hip_bf16.h>

// ---------------------------------------------------------------------------
// Sizes (fixed by the reference):
//   x_e  [2,128,24,24,24]   pred [2,32,96,96,96]
//   conv: 128->256, k=3, s=2, VALID -> out spatial 11^3 = 1331
//   out  [2,3,96,96,96] fp32
// ---------------------------------------------------------------------------

#define NSPAT 13824      // 24*24*24
#define NPOS  1331       // 11^3
#define P4    221184     // 96^3 / 4

// K1: per-(b,group) mean & rstd.  32 blocks x 256 threads.
__global__ __launch_bounds__(256) void gn_stats_kernel(
    const float* __restrict__ x, float* __restrict__ stats) {
  int bg = blockIdx.x;                               // b*16+g
  const float4* p = (const float4*)(x + (size_t)bg * 110592);
  float s = 0.f, ss = 0.f;
  for (int i = threadIdx.x; i < 27648; i += 256) {
    float4 v = p[i];
    s  += v.x + v.y + v.z + v.w;
    ss += v.x*v.x + v.y*v.y + v.z*v.z + v.w*v.w;
  }
  #pragma unroll
  for (int off = 32; off; off >>= 1) {
    s  += __shfl_down(s, off);
    ss += __shfl_down(ss, off);
  }
  __shared__ float a[4], b2[4];
  int wid = threadIdx.x >> 6, lane = threadIdx.x & 63;
  if (lane == 0) { a[wid] = s; b2[wid] = ss; }
  __syncthreads();
  if (threadIdx.x == 0) {
    float S  = a[0] + a[1] + a[2] + a[3];
    float SS = b2[0] + b2[1] + b2[2] + b2[3];
    float mu = S * (1.f / 110592.f);
    float var = SS * (1.f / 110592.f) - mu * mu;
    stats[bg * 2]     = mu;
    stats[bg * 2 + 1] = rsqrtf(var + 1e-5f);
  }
}

// K2: per-(b,c) GN+ReLU staged in LDS, then 27 strided window sums.
// 256 blocks x 256 threads.  wins[b*3456 + c*27 + k]
__global__ __launch_bounds__(256) void gn_relu_winsum_kernel(
    const float* __restrict__ x, const float* __restrict__ stats,
    const float* __restrict__ gn_g, const float* __restrict__ gn_b,
    float* __restrict__ wins) {
  int bc = blockIdx.x;
  int b = bc >> 7, c = bc & 127;
  int g = c >> 3;
  float mu = stats[(b * 16 + g) * 2], rstd = stats[(b * 16 + g) * 2 + 1];
  float ga = gn_g[c] * rstd;
  float be = gn_b[c] - mu * ga;            // y = x*ga + be

  __shared__ float lds[NSPAT];
  __shared__ float part[4][27];
  const float4* p = (const float4*)(x + (size_t)bc * NSPAT);
  float4* l4 = (float4*)lds;
  for (int i = threadIdx.x; i < NSPAT / 4; i += 256) {
    float4 v = p[i];
    float4 r;
    r.x = fmaxf(v.x * ga + be, 0.f);
    r.y = fmaxf(v.y * ga + be, 0.f);
    r.z = fmaxf(v.z * ga + be, 0.f);
    r.w = fmaxf(v.w * ga + be, 0.f);
    l4[i] = r;
  }
  __syncthreads();

  float acc[27];
  #pragma unroll
  for (int k = 0; k < 27; k++) acc[k] = 0.f;
  for (int pidx = threadIdx.x; pidx < NPOS; pidx += 256) {
    int z = pidx / 121, rem = pidx % 121;
    int y = rem / 11, xx = rem % 11;
    int base = z * 1152 + y * 48 + xx * 2;   // (2z)*576 + (2y)*24 + 2x
    #pragma unroll
    for (int kz = 0; kz < 3; kz++)
      #pragma unroll
      for (int ky = 0; ky < 3; ky++)
        #pragma unroll
        for (int kx = 0; kx < 3; kx++)
          acc[kz * 9 + ky * 3 + kx] += lds[base + kz * 576 + ky * 24 + kx];
  }
  #pragma unroll
  for (int k = 0; k < 27; k++)
    for (int off = 32; off; off >>= 1)
      acc[k] += __shfl_down(acc[k], off);
  int wid = threadIdx.x >> 6, lane = threadIdx.x & 63;
  if (lane == 0)
    #pragma unroll
    for (int k = 0; k < 27; k++) part[wid][k] = acc[k];
  __syncthreads();
  if (threadIdx.x < 27) {
    float v = part[0][threadIdx.x] + part[1][threadIdx.x] +
              part[2][threadIdx.x] + part[3][threadIdx.x];
    wins[b * 3456 + c * 27 + threadIdx.x] = v;
  }
}

// K3: x_feat[b,o] = dot(wins[b,:], gap_w[o,:]) / 1331 + gap_b[o]
// grid 32 blocks (b*16+ochunk), 256 threads, 8 outputs/block, 32 lanes/output.
__global__ __launch_bounds__(256) void xfeat_kernel(
    const float* __restrict__ wins, const float* __restrict__ gap_w,
    const float* __restrict__ gap_b, float* __restrict__ xf) {
  int b = blockIdx.x >> 4;
  int ochunk = blockIdx.x & 15;
  __shared__ float sl[3456];
  for (int i = threadIdx.x; i < 3456; i += 256) sl[i] = wins[b * 3456 + i];
  __syncthreads();
  int olocal = threadIdx.x >> 5;     // 0..7
  int lane32 = threadIdx.x & 31;
  int o = ochunk * 8 + olocal;       // hmm: 16 chunks * 8 = 128... need 256
  o = ochunk * 16 + olocal;          // placeholder overwritten below
  // correct mapping: 16 chunks of 16 outputs would need 512 threads;
  // use 8 outputs per block over 32 chunks instead -> recompute:
  o = (blockIdx.x & 31);             // unused guard
  // Final (clean) mapping: blockIdx.x in [0,64): b = blockIdx.x>>5, 8 outs
  // --- replaced below by launch config: grid = 64 blocks ---
  b = blockIdx.x >> 5;
  int oc = blockIdx.x & 31;          // 32 chunks of 8 outputs
  o = oc * 8 + olocal;
  __syncthreads();
  const float4* w4 = (const float4*)(gap_w + (size_t)o * 3456);
  const float4* s4 = (const float4*)sl;
  float acc = 0.f;
  for (int i = lane32; i < 864; i += 32) {
    float4 wv = w4[i], sv = s4[i];
    acc += wv.x * sv.x + wv.y * sv.y + wv.z * sv.z + wv.w * sv.w;
  }
  #pragma unroll
  for (int off = 16; off; off >>= 1) acc += __shfl_down(acc, off, 32);
  if (lane32 == 0) xf[b * 256 + o] = acc * (1.f / 1331.f) + gap_b[o];
}

// K4: controller chain per (b,k).  6 blocks x 256 threads.
__global__ __launch_bounds__(256) void controller_kernel(
    const float* __restrict__ xf, const float* __restrict__ emb,
    const float* __restrict__ w_cf, const float* __restrict__ b_cf,
    const float* __restrict__ w_c,  const float* __restrict__ b_c,
    const float* __restrict__ w_a1, const float* __restrict__ b_a1,
    const float* __restrict__ w_a2, const float* __restrict__ b_a2,
    const float* __restrict__ w_seg, float* __restrict__ effw) {
  int bk = blockIdx.x;
  int b = bk / 3, k = bk % 3;
  __shared__ float cond[512], pbuf[512], cbuf[256], hid[16];
  int t = threadIdx.x;
  for (int i = t; i < 512; i += 256)
    cond[i] = (i < 256) ? xf[b * 256 + i] : emb[k * 256 + (i - 256)];
  __syncthreads();
  for (int o = t; o < 512; o += 256) {
    const float4* w4 = (const float4*)(w_cf + (size_t)o * 512);
    const float4* c4 = (const float4*)cond;
    float acc = 0.f;
    for (int j = 0; j < 128; j++) {
      float4 wv = w4[j], cv = c4[j];
      acc += wv.x * cv.x + wv.y * cv.y + wv.z * cv.z + wv.w * cv.w;
    }
    pbuf[o] = fmaxf(acc + b_cf[o], 0.f);
  }
  __syncthreads();
  if (t < 256) {
    const float4* w4 = (const float4*)(w_c + (size_t)t * 512);
    const float4* p4 = (const float4*)pbuf;
    float acc = 0.f;
    for (int j = 0; j < 128; j++) {
      float4 wv = w4[j], pv = p4[j];
      acc += wv.x * pv.x + wv.y * pv.y + wv.z * pv.z + wv.w * pv.w;
    }
    cbuf[t] = acc + b_c[t];
  }
  __syncthreads();
  if (t < 16) {
    float acc = b_a1[t];
    for (int j = 0; j < 256; j++) acc += w_a1[t * 256 + j] * cbuf[j];
    hid[t] = fmaxf(acc, 0.f);
  }
  __syncthreads();
  if (t < 32) {
    float acc = b_a2[t];
    #pragma unroll
    for (int j = 0; j < 16; j++) acc += w_a2[t * 16 + j] * hid[j];
    float gate = 1.f / (1.f + expf(-acc));
    effw[bk * 32 + t] = gate * w_seg[k * 32 + t];
  }
}

// K5: out[b,k,p] = sum_c effw[b,k,c]*pred[b,c,p] + b_seg[k]
// float4 over p.  1728 blocks x 256 threads.
__global__ __launch_bounds__(256) void seg_kernel(
    const float* __restrict__ pred, const float* __restrict__ effw,
    const float* __restrict__ b_seg, float* __restrict__ out) {
  __shared__ float ew[192];
  if (threadIdx.x < 192) ew[threadIdx.x] = effw[threadIdx.x];
  __syncthreads();
  int gid = blockIdx.x * 256 + threadIdx.x;     // < 442368
  int b = gid / P4;
  int p = gid - b * P4;
  const float4* pr = (const float4*)pred + (size_t)b * 32 * P4 + p;
  const float* e = ew + b * 96;
  float4 a0 = {0, 0, 0, 0}, a1 = a0, a2 = a0;
  #pragma unroll 8
  for (int c = 0; c < 32; c++) {
    float4 v = pr[(size_t)c * P4];
    float w0 = e[c], w1 = e[32 + c], w2 = e[64 + c];
    a0.x += w0 * v.x; a0.y += w0 * v.y; a0.z += w0 * v.z; a0.w += w0 * v.w;
    a1.x += w1 * v.x; a1.y += w1 * v.y; a1.z += w1 * v.z; a1.w += w1 * v.w;
    a2.x += w2 * v.x; a2.y += w2 * v.y; a2.z += w2 * v.z; a2.w += w2 * v.w;
  }
  float s0 = b_seg[0], s1 = b_seg[1], s2 = b_seg[2];
  a0.x += s0; a0.y += s0; a0.z += s0; a0.w += s0;
  a1.x += s1; a1.y += s1; a1.z += s1; a1.w += s1;
  a2.x += s2; a2.y += s2; a2.z += s2; a2.w += s2;
  float4* o4 = (float4*)out + (size_t)b * 3 * P4 + p;
  o4[0]      = a0;
  o4[P4]     = a1;
  o4[2 * P4] = a2;
}

extern "C" void kernel_launch(void* const* d_in, const int* in_sizes, int n_in,
                              void* d_out, int out_size, void* d_ws, size_t ws_size,
                              hipStream_t stream) {
  const float* x_e   = (const float*)d_in[0];
  const float* pred  = (const float*)d_in[1];
  const float* gn_g  = (const float*)d_in[2];
  const float* gn_b  = (const float*)d_in[3];
  const float* gap_w = (const float*)d_in[4];
  const float* gap_b = (const float*)d_in[5];
  const float* w_cf  = (const float*)d_in[6];
  const float* b_cf  = (const float*)d_in[7];
  const float* w_c   = (const float*)d_in[8];
  const float* b_c   = (const float*)d_in[9];
  const float* w_a1  = (const float*)d_in[10];
  const float* b_a1  = (const float*)d_in[11];
  const float* w_a2  = (const float*)d_in[12];
  const float* b_a2  = (const float*)d_in[13];
  const float* emb   = (const float*)d_in[14];
  const float* w_seg = (const float*)d_in[15];
  const float* b_seg = (const float*)d_in[16];

  float* ws    = (float*)d_ws;
  float* stats = ws;            // 64 floats
  float* wins  = ws + 64;       // 6912 floats
  float* xf    = ws + 6976;     // 512 floats
  float* effw  = ws + 7488;     // 192 floats
  float* out   = (float*)d_out;

  gn_stats_kernel<<<32, 256, 0, stream>>>(x_e, stats);
  gn_relu_winsum_kernel<<<256, 256, 0, stream>>>(x_e, stats, gn_g, gn_b, wins);
  xfeat_kernel<<<64, 256, 0, stream>>>(wins, gap_w, gap_b, xf);
  controller_kernel<<<6, 256, 0, stream>>>(xf, emb, w_cf, b_cf, w_c, b_c,
                                           w_a1, b_a1, w_a2, b_a2, w_seg, effw);
  seg_kernel<<<1728, 256, 0, stream>>>(pred, effw, b_seg, out);
}

// Round 2
// 100.149 us; speedup vs baseline: 1.5518x; 1.5518x over previous
//
#include <hip/hip_runtime.h>
#include <hip/hip_bf16.h>

// ---------------------------------------------------------------------------
// Sizes (fixed by the reference):
//   x_e  [2,128,24,24,24]   pred [2,32,96,96,96]
//   conv: 128->256, k=3, s=2, VALID -> out spatial 11^3 = 1331
//   out  [2,3,96,96,96] fp32
//
// Decomposition (exact, by linearity of mean∘conv):
//   wins[b,c,tap] = sum over 11^3 output positions of relu(gn(x_e))[input tap]
//   x_feat[b,o]   = dot(wins[b,:], gap_w[o,:]) / 1331 + gap_b[o]
//   controller MLP chain -> effw[b,k,c] = sigmoid(...)*w_seg[k,c]
//   out[b,k,p]    = sum_c effw[b,k,c]*pred[b,c,p] + b_seg[k]
// ---------------------------------------------------------------------------

#define NSPAT 13824      // 24*24*24
#define P4    221184     // 96^3 / 4

// ws layout (floats)
#define WS_STATSPART 0       // 512 x float2 -> 1024
#define WS_WINS      1024    // [2][128][2][27] = 13824
#define WS_XF        14848   // 512
#define WS_P         15360   // 6*512 = 3072
#define WS_C         18432   // 6*256 = 1536
#define WS_EFFW      19968   // 192
#define WS_SINK      20160   // 1

// ---------------------------------------------------------------------------
// K1: partial GN stats.  blocks 0..511: (b*16+g)*16+chunk, each sums 6912
// elements of its group.  blocks 512..575: prefetch gap_w/w_cf/w_c into L3.
// ---------------------------------------------------------------------------
__global__ __launch_bounds__(256) void gn_stats_part_kernel(
    const float* __restrict__ x, const float* __restrict__ gap_w,
    const float* __restrict__ w_cf, const float* __restrict__ w_c,
    float* __restrict__ ws) {
  if (blockIdx.x >= 512) {
    // L3 prefetch role
    float s = 0.f;
    int tid = (blockIdx.x - 512) * 256 + threadIdx.x;   // 0..16383
    const float4* g4 = (const float4*)gap_w;            // 221184 f4
    const float4* a4 = (const float4*)w_cf;             // 65536 f4
    const float4* c4 = (const float4*)w_c;              // 32768 f4
    for (int i = tid; i < 221184; i += 16384) { float4 v = g4[i]; s += v.x + v.w; }
    for (int i = tid; i < 65536;  i += 16384) { float4 v = a4[i]; s += v.x + v.w; }
    for (int i = tid; i < 32768;  i += 16384) { float4 v = c4[i]; s += v.x + v.w; }
    if (s == 1.2345e30f) ws[WS_SINK] = s;   // keep loads alive; never taken
    return;
  }
  int blk = blockIdx.x;                     // bg*16 + chunk
  const float4* p = (const float4*)(x + (size_t)blk * 6912);
  float s = 0.f, ss = 0.f;
  for (int i = threadIdx.x; i < 1728; i += 256) {
    float4 v = p[i];
    s  += v.x + v.y + v.z + v.w;
    ss += v.x*v.x + v.y*v.y + v.z*v.z + v.w*v.w;
  }
  #pragma unroll
  for (int off = 32; off; off >>= 1) {
    s  += __shfl_down(s, off);
    ss += __shfl_down(ss, off);
  }
  __shared__ float a[4], b2[4];
  int wid = threadIdx.x >> 6, lane = threadIdx.x & 63;
  if (lane == 0) { a[wid] = s; b2[wid] = ss; }
  __syncthreads();
  if (threadIdx.x == 0) {
    float2 r;
    r.x = a[0] + a[1] + a[2] + a[3];
    r.y = b2[0] + b2[1] + b2[2] + b2[3];
    ((float2*)(ws + WS_STATSPART))[blk] = r;
  }
}

// ---------------------------------------------------------------------------
// K2: per-(b,c,zhalf) GN+ReLU staged in LDS, 27 strided window partial sums.
// 512 blocks x 256 threads.  zh=0: out z 0..5 (726 pos), input planes 0..12.
//                            zh=1: out z 6..10 (605 pos), input planes 12..22.
// local input plane index = 2*zl + kz for both halves.
// winsP[((b*128+c)*2+zh)*27 + tap]
// ---------------------------------------------------------------------------
__global__ __launch_bounds__(256) void gn_relu_winsum_kernel(
    const float* __restrict__ x, const float* __restrict__ gn_g,
    const float* __restrict__ gn_b, float* __restrict__ ws) {
  int blk = blockIdx.x;
  int zh = blk & 1;
  int bc = blk >> 1;
  int b = bc >> 7, c = bc & 127;
  int bg = b * 16 + (c >> 3);

  // finalize group stats from 16 partials (redundant per block, cheap)
  const float2* sp = (const float2*)(ws + WS_STATSPART) + bg * 16;
  float S = 0.f, SS = 0.f;
  #pragma unroll
  for (int j = 0; j < 16; j++) { float2 r = sp[j]; S += r.x; SS += r.y; }
  float mu = S * (1.f / 110592.f);
  float var = SS * (1.f / 110592.f) - mu * mu;
  float rstd = rsqrtf(var + 1e-5f);
  float ga = gn_g[c] * rstd;
  float be = gn_b[c] - mu * ga;

  __shared__ float lds[7488];          // up to 13 planes * 576
  __shared__ float part[4][27];
  int planes = zh ? 11 : 13;
  int startf = zh ? 6912 : 0;          // 12*576
  int nf4 = planes * 144;              // planes*576/4
  const float4* p = (const float4*)(x + (size_t)bc * NSPAT + startf);
  float4* l4 = (float4*)lds;
  for (int i = threadIdx.x; i < nf4; i += 256) {
    float4 v = p[i];
    float4 r;
    r.x = fmaxf(v.x * ga + be, 0.f);
    r.y = fmaxf(v.y * ga + be, 0.f);
    r.z = fmaxf(v.z * ga + be, 0.f);
    r.w = fmaxf(v.w * ga + be, 0.f);
    l4[i] = r;
  }
  __syncthreads();

  float acc[27];
  #pragma unroll
  for (int k = 0; k < 27; k++) acc[k] = 0.f;
  int npos = zh ? 605 : 726;           // (5 or 6) * 121
  for (int pidx = threadIdx.x; pidx < npos; pidx += 256) {
    int zl = pidx / 121, rem = pidx % 121;
    int y = rem / 11, xx = rem % 11;
    int base = zl * 1152 + y * 48 + xx * 2;   // (2zl)*576 + (2y)*24 + 2x
    #pragma unroll
    for (int kz = 0; kz < 3; kz++)
      #pragma unroll
      for (int ky = 0; ky < 3; ky++)
        #pragma unroll
        for (int kx = 0; kx < 3; kx++)
          acc[kz * 9 + ky * 3 + kx] += lds[base + kz * 576 + ky * 24 + kx];
  }
  #pragma unroll
  for (int k = 0; k < 27; k++)
    for (int off = 32; off; off >>= 1)
      acc[k] += __shfl_down(acc[k], off);
  int wid = threadIdx.x >> 6, lane = threadIdx.x & 63;
  if (lane == 0)
    #pragma unroll
    for (int k = 0; k < 27; k++) part[wid][k] = acc[k];
  __syncthreads();
  if (threadIdx.x < 27) {
    float v = part[0][threadIdx.x] + part[1][threadIdx.x] +
              part[2][threadIdx.x] + part[3][threadIdx.x];
    ws[WS_WINS + blk * 27 + threadIdx.x] = v;
  }
}

// ---------------------------------------------------------------------------
// K3: x_feat[b,o] = dot(wins[b,:], gap_w[o,:]) / 1331 + gap_b[o]
// 64 blocks x 256: b = blk>>5, 32 chunks of 8 outputs, 32 lanes/output.
// ---------------------------------------------------------------------------
__global__ __launch_bounds__(256) void xfeat_kernel(
    const float* __restrict__ ws_in, const float* __restrict__ gap_w,
    const float* __restrict__ gap_b, float* __restrict__ ws_out) {
  int b = blockIdx.x >> 5;
  int oc = blockIdx.x & 31;
  __shared__ float sl[3456];
  const float* wp = ws_in + WS_WINS + b * 6912;   // [c][2][27]
  for (int i = threadIdx.x; i < 3456; i += 256) {
    int c = i / 27, k = i - c * 27;
    sl[i] = wp[c * 54 + k] + wp[c * 54 + 27 + k];
  }
  __syncthreads();
  int olocal = threadIdx.x >> 5;
  int lane32 = threadIdx.x & 31;
  int o = oc * 8 + olocal;
  const float4* w4 = (const float4*)(gap_w + (size_t)o * 3456);
  const float4* s4 = (const float4*)sl;
  float acc = 0.f;
  for (int i = lane32; i < 864; i += 32) {
    float4 wv = w4[i], sv = s4[i];
    acc += wv.x * sv.x + wv.y * sv.y + wv.z * sv.z + wv.w * sv.w;
  }
  #pragma unroll
  for (int off = 16; off; off >>= 1) acc += __shfl_down(acc, off, 32);
  if (lane32 == 0) ws_out[WS_XF + b * 256 + o] = acc * (1.f / 1331.f) + gap_b[o];
}

// ---------------------------------------------------------------------------
// K4a: p[bk,o] = relu(W_cf . cond + b_cf).  24 blocks = bk*4 + q.
// 128 outputs/block, 2 threads per output (split dot in half).
// ---------------------------------------------------------------------------
__global__ __launch_bounds__(256) void ctrl1_kernel(
    const float* __restrict__ ws_in, const float* __restrict__ emb,
    const float* __restrict__ w_cf, const float* __restrict__ b_cf,
    float* __restrict__ ws_out) {
  int bk = blockIdx.x >> 2;
  int q = blockIdx.x & 3;
  int b = bk / 3, k = bk % 3;
  __shared__ float cond[512];
  __shared__ float ph[2][128];
  int t = threadIdx.x;
  for (int i = t; i < 512; i += 256)
    cond[i] = (i < 256) ? ws_in[WS_XF + b * 256 + i] : emb[k * 256 + (i - 256)];
  __syncthreads();
  int ol = t & 127, half = t >> 7;
  int o = q * 128 + ol;
  const float4* w4 = (const float4*)(w_cf + (size_t)o * 512) + half * 64;
  const float4* c4 = (const float4*)cond + half * 64;
  float acc = 0.f;
  #pragma unroll 8
  for (int j = 0; j < 64; j++) {
    float4 wv = w4[j], cv = c4[j];
    acc += wv.x * cv.x + wv.y * cv.y + wv.z * cv.z + wv.w * cv.w;
  }
  ph[half][ol] = acc;
  __syncthreads();
  if (t < 128)
    ws_out[WS_P + bk * 512 + o] = fmaxf(ph[0][t] + ph[1][t] + b_cf[o], 0.f);
}

// ---------------------------------------------------------------------------
// K4b: c[bk,o] = W_c . p + b_c.  12 blocks = bk*2 + h.  128 outs/block.
// ---------------------------------------------------------------------------
__global__ __launch_bounds__(256) void ctrl2_kernel(
    const float* __restrict__ ws_in, const float* __restrict__ w_c,
    const float* __restrict__ b_c, float* __restrict__ ws_out) {
  int bk = blockIdx.x >> 1;
  int h = blockIdx.x & 1;
  __shared__ float pbuf[512];
  __shared__ float ph[2][128];
  int t = threadIdx.x;
  for (int i = t; i < 512; i += 256) pbuf[i] = ws_in[WS_P + bk * 512 + i];
  __syncthreads();
  int ol = t & 127, half = t >> 7;
  int o = h * 128 + ol;
  const float4* w4 = (const float4*)(w_c + (size_t)o * 512) + half * 64;
  const float4* p4 = (const float4*)pbuf + half * 64;
  float acc = 0.f;
  #pragma unroll 8
  for (int j = 0; j < 64; j++) {
    float4 wv = w4[j], pv = p4[j];
    acc += wv.x * pv.x + wv.y * pv.y + wv.z * pv.z + wv.w * pv.w;
  }
  ph[half][ol] = acc;
  __syncthreads();
  if (t < 128)
    ws_out[WS_C + bk * 256 + o] = ph[0][t] + ph[1][t] + b_c[o];
}

// ---------------------------------------------------------------------------
// K4c: hid = relu(W_a1.c + b_a1); gate = sigmoid(W_a2.hid + b_a2);
//      effw[bk,c] = gate*w_seg[k,c].  6 blocks x 64 threads.
// ---------------------------------------------------------------------------
__global__ __launch_bounds__(64) void ctrl3_kernel(
    const float* __restrict__ ws_in,
    const float* __restrict__ w_a1, const float* __restrict__ b_a1,
    const float* __restrict__ w_a2, const float* __restrict__ b_a2,
    const float* __restrict__ w_seg, float* __restrict__ ws_out) {
  int bk = blockIdx.x;
  int k = bk % 3;
  __shared__ float cbuf[256], hid[16];
  int t = threadIdx.x;
  for (int i = t; i < 256; i += 64) cbuf[i] = ws_in[WS_C + bk * 256 + i];
  __syncthreads();
  if (t < 16) {
    float acc = b_a1[t];
    const float4* w4 = (const float4*)(w_a1 + t * 256);
    const float4* c4 = (const float4*)cbuf;
    for (int j = 0; j < 64; j++) {
      float4 wv = w4[j], cv = c4[j];
      acc += wv.x * cv.x + wv.y * cv.y + wv.z * cv.z + wv.w * cv.w;
    }
    hid[t] = fmaxf(acc, 0.f);
  }
  __syncthreads();
  if (t < 32) {
    float acc = b_a2[t];
    #pragma unroll
    for (int j = 0; j < 16; j++) acc += w_a2[t * 16 + j] * hid[j];
    float gate = 1.f / (1.f + expf(-acc));
    ws_out[WS_EFFW + bk * 32 + t] = gate * w_seg[k * 32 + t];
  }
}

// ---------------------------------------------------------------------------
// K5: out[b,k,p] = sum_c effw[b,k,c]*pred[b,c,p] + b_seg[k]
// 1728 blocks x 256 threads, float4 over p.
// ---------------------------------------------------------------------------
__global__ __launch_bounds__(256) void seg_kernel(
    const float* __restrict__ pred, const float* __restrict__ ws_in,
    const float* __restrict__ b_seg, float* __restrict__ out) {
  __shared__ float ew[192];
  if (threadIdx.x < 192) ew[threadIdx.x] = ws_in[WS_EFFW + threadIdx.x];
  __syncthreads();
  int gid = blockIdx.x * 256 + threadIdx.x;     // < 442368 exactly
  int b = gid / P4;
  int p = gid - b * P4;
  const float4* pr = (const float4*)pred + (size_t)b * 32 * P4 + p;
  const float* e = ew + b * 96;
  float4 a0 = {0, 0, 0, 0}, a1 = a0, a2 = a0;
  #pragma unroll 8
  for (int c = 0; c < 32; c++) {
    float4 v = pr[(size_t)c * P4];
    float w0 = e[c], w1 = e[32 + c], w2 = e[64 + c];
    a0.x += w0 * v.x; a0.y += w0 * v.y; a0.z += w0 * v.z; a0.w += w0 * v.w;
    a1.x += w1 * v.x; a1.y += w1 * v.y; a1.z += w1 * v.z; a1.w += w1 * v.w;
    a2.x += w2 * v.x; a2.y += w2 * v.y; a2.z += w2 * v.z; a2.w += w2 * v.w;
  }
  float s0 = b_seg[0], s1 = b_seg[1], s2 = b_seg[2];
  a0.x += s0; a0.y += s0; a0.z += s0; a0.w += s0;
  a1.x += s1; a1.y += s1; a1.z += s1; a1.w += s1;
  a2.x += s2; a2.y += s2; a2.z += s2; a2.w += s2;
  float4* o4 = (float4*)out + (size_t)b * 3 * P4 + p;
  o4[0]      = a0;
  o4[P4]     = a1;
  o4[2 * P4] = a2;
}

extern "C" void kernel_launch(void* const* d_in, const int* in_sizes, int n_in,
                              void* d_out, int out_size, void* d_ws, size_t ws_size,
                              hipStream_t stream) {
  const float* x_e   = (const float*)d_in[0];
  const float* pred  = (const float*)d_in[1];
  const float* gn_g  = (const float*)d_in[2];
  const float* gn_b  = (const float*)d_in[3];
  const float* gap_w = (const float*)d_in[4];
  const float* gap_b = (const float*)d_in[5];
  const float* w_cf  = (const float*)d_in[6];
  const float* b_cf  = (const float*)d_in[7];
  const float* w_c   = (const float*)d_in[8];
  const float* b_c   = (const float*)d_in[9];
  const float* w_a1  = (const float*)d_in[10];
  const float* b_a1  = (const float*)d_in[11];
  const float* w_a2  = (const float*)d_in[12];
  const float* b_a2  = (const float*)d_in[13];
  const float* emb   = (const float*)d_in[14];
  const float* w_seg = (const float*)d_in[15];
  const float* b_seg = (const float*)d_in[16];

  float* ws  = (float*)d_ws;
  float* out = (float*)d_out;

  gn_stats_part_kernel<<<576, 256, 0, stream>>>(x_e, gap_w, w_cf, w_c, ws);
  gn_relu_winsum_kernel<<<512, 256, 0, stream>>>(x_e, gn_g, gn_b, ws);
  xfeat_kernel<<<64, 256, 0, stream>>>(ws, gap_w, gap_b, ws);
  ctrl1_kernel<<<24, 256, 0, stream>>>(ws, emb, w_cf, b_cf, ws);
  ctrl2_kernel<<<12, 256, 0, stream>>>(ws, w_c, b_c, ws);
  ctrl3_kernel<<<6, 64, 0, stream>>>(ws, w_a1, b_a1, w_a2, b_a2, w_seg, ws);
  seg_kernel<<<1728, 256, 0, stream>>>(pred, ws, b_seg, out);
}